// Round 21
// baseline (1792.588 us; speedup 1.0000x reference)
//
#include <hip/hip_runtime.h>

typedef unsigned int u32;
typedef unsigned long long u64;
typedef unsigned short u16;
typedef __attribute__((ext_vector_type(8))) short bf16x8;
typedef __attribute__((ext_vector_type(4))) float f32x4;

#define DEV __device__ __forceinline__

DEV float sq3(float x, float y, float z) {
#pragma clang fp contract(off)
  return (x * x + y * y) + z * z;
}
DEV float knn_sqd(float4 Q, float4 p) {
#pragma clang fp contract(off)
  float dot = (Q.x * p.x + Q.y * p.y) + Q.z * p.z;
  return (Q.w + p.w) - 2.0f * dot;
}
DEV float dot4(float4 a, float4 b) {
  return (a.x * b.x + a.y * b.y) + (a.z * b.z + a.w * b.w);
}
DEV u32 f2bfu(float f) {
  u32 u = __float_as_uint(f);
  return (u + 0x7fffu + ((u >> 16) & 1u)) >> 16;
}
DEV f32x4 MFMA(bf16x8 a, bf16x8 b, f32x4 c) {
  return __builtin_amdgcn_mfma_f32_16x16x32_bf16(a, b, c, 0, 0, 0);
}

// ---------- weight table (f32) ----------
enum : int {
  W_PEW1 = 0, W_PEB1 = 192, W_BNG = 256, W_BNB = 320,
  W_PEW2 = 384, W_PEB2 = 8576,
  W_INW  = 8704,   W_INB  = 107008,
  W_OUTW = 107776, W_OUTB = 140544,
  W_LN1G = 140800, W_LN1B = 141056, W_LN2G = 141312, W_LN2B = 141568,
  W_FF1W = 141824, W_FF1B = 207360,
  W_FF2W = 207872, W_FF2B = 273408,
  W_FCW  = 273664, W_FCB  = 306432,
  W_TOTAL = 306688
};
enum : int { WP_QB = 0, WP_FB = 768, WP_TOTAL = 1280 };
enum : int {
  WB_Q  = 0,       // [2][384][128]
  WB_O  = 98304,   // [2][128][128]
  WB_F1 = 131072,  // [2][256][128]
  WB_F2 = 196608,  // [2][128][256]
  WB_P2 = 262144,  // [128][64]
  WB_TOTAL = 270336
};

// ws byte offsets
static const size_t OFF_XYZW  = 1226752;
static const size_t OFF_NEWX  = 1751040;
static const size_t OFF_KNN   = 1882112;
static const size_t OFF_WP    = 2930688;
static const size_t OFF_WB    = 2936064;
static const size_t OFF_FLAGS = 3476736;  // int[8192]
static const size_t OFF_FEATT = 3509504;  // OPTIONAL [8][4096][128] f32
static const size_t END_BIG   = 20286720;

struct WArgs { const float* p[20]; };

// ---------- k_pre: blocks 0..7 FPS (raw xyz); then transpose; then setup ----------
__global__ __launch_bounds__(256, 1) void k_pre(
    WArgs a, float* __restrict__ wf, float* __restrict__ wp,
    u16* __restrict__ wb, const float* __restrict__ xyz,
    float4* __restrict__ xyzw, float4* __restrict__ new_xyzw,
    float* __restrict__ out_xyz, const float* __restrict__ feat,
    float* __restrict__ featT, const int useT) {
  __shared__ __align__(16) float4 PS[4096];
  __shared__ u64 wkk[2][4];
  __shared__ float tile[32][33];
  const int tid = threadIdx.x;
  const int blk = blockIdx.x;
  if (blk >= 8) {
    if (useT && blk < 4104) {
      // transpose: features [B][128][4096] -> featT [B][4096][128]
      const int bb = blk - 8;
      const int b = bb >> 9, r2 = bb & 511;
      const int n0 = (r2 >> 2) << 5, c0 = (r2 & 3) << 5;
      const int tx = tid & 31, ty = tid >> 5;
#pragma unroll
      for (int i = 0; i < 4; ++i) {
        const int c = c0 + ty + (i << 3);
        tile[ty + (i << 3)][tx] =
            __builtin_nontemporal_load(&feat[(size_t)b * 524288 + (size_t)c * 4096 + n0 + tx]);
      }
      __syncthreads();
#pragma unroll
      for (int i = 0; i < 4; ++i) {
        const int n = n0 + ty + (i << 3);
        __builtin_nontemporal_store(tile[tx][ty + (i << 3)],
            &featT[(size_t)b * 524288 + (size_t)n * 128 + c0 + tx]);
      }
      return;
    }
    // ---- setup region ----
    const int sblk = blk - (useT ? 4104 : 8);
    if (sblk < 1198) {
      const int idx = sblk * 256 + tid;
      if (idx >= W_TOTAL) return;
      const int sz[20] = {192, 64, 64, 64, 8192, 128, 98304, 768, 32768, 256,
                          256, 256, 256, 256, 65536, 512, 65536, 256, 32768, 256};
      int rem = idx;
#pragma unroll
      for (int s = 0; s < 20; ++s) {
        if (rem < sz[s]) { wf[idx] = a.p[s][rem]; return; }
        rem -= sz[s];
      }
      return;
    }
    if (sblk < 1206) {
      const int idx = (sblk - 1198) * 256 + tid;
      if (idx >= 1920) return;
      if (idx < 768) {  // qkv: fold ln1
        const int l = idx / 384, o = idx % 384;
        const float* W = a.p[6] + l * 49152 + o * 128;
        const float* G = a.p[10] + l * 128;
        const float* Bl = a.p[11] + l * 128;
        float acc = a.p[7][l * 384 + o];
        u16* ph = wb + WB_Q + (l * 384 + o) * 128;
        for (int c = 0; c < 128; ++c) {
          const float w = W[c];
          acc += Bl[c] * w;
          ph[c] = (u16)f2bfu(w * G[c]);
        }
        wp[WP_QB + l * 384 + o] = acc;
      } else if (idx < 1280) {  // ff1: fold ln2
        const int j2 = idx - 768, l = j2 / 256, o = j2 % 256;
        const float* W = a.p[14] + l * 32768 + o * 128;
        const float* G = a.p[12] + l * 128;
        const float* Bl = a.p[13] + l * 128;
        float acc = a.p[15][l * 256 + o];
        u16* ph = wb + WB_F1 + (l * 256 + o) * 128;
        for (int c = 0; c < 128; ++c) {
          const float w = W[c];
          acc += Bl[c] * w;
          ph[c] = (u16)f2bfu(w * G[c]);
        }
        wp[WP_FB + l * 256 + o] = acc;
      } else if (idx < 1536) {  // out-proj
        const int j2 = idx - 1280, l = j2 / 128, o = j2 % 128;
        const float* W = a.p[8] + l * 16384 + o * 128;
        u16* ph = wb + WB_O + (l * 128 + o) * 128;
        for (int c = 0; c < 128; ++c) ph[c] = (u16)f2bfu(W[c]);
      } else if (idx < 1792) {  // ff2
        const int j2 = idx - 1536, l = j2 / 128, o = j2 % 128;
        const float* W = a.p[16] + l * 32768 + o * 256;
        u16* ph = wb + WB_F2 + (l * 128 + o) * 256;
        for (int c = 0; c < 256; ++c) ph[c] = (u16)f2bfu(W[c]);
      } else {  // pe_w2
        const int o = idx - 1792;
        const float* W = a.p[4] + o * 64;
        u16* ph = wb + WB_P2 + o * 64;
        for (int c = 0; c < 64; ++c) ph[c] = (u16)f2bfu(W[c]);
      }
      return;
    }
    {
      const int i = (sblk - 1206) * 256 + tid;
      const int b = i >> 12, n = i & 4095;
      const size_t s = (size_t)b * 12288 + n;
      float x = xyz[s], y = xyz[s + 4096], z = xyz[s + 8192];
      xyzw[i] = make_float4(x, y, z, sq3(x, y, z));
      return;
    }
  }
  // ---- FPS — exact replica of reference scan (reads raw xyz) ----
  const int b = blk;
  const size_t sb = (size_t)b * 12288;
  float px[16], py[16], pz[16], dm[16];
#pragma unroll
  for (int j = 0; j < 16; ++j) {
    const int n = tid * 16 + j;
    float x = xyz[sb + n], y = xyz[sb + 4096 + n], z = xyz[sb + 8192 + n];
    PS[n] = make_float4(x, y, z, 0.f);
    px[j] = x; py[j] = y; pz[j] = z; dm[j] = 1e10f;
  }
  __syncthreads();
  float4 c0 = PS[0];
  float cx = c0.x, cy = c0.y, cz = c0.z;
  if (tid == 0) {
    new_xyzw[(size_t)b * 1024] = make_float4(cx, cy, cz, sq3(cx, cy, cz));
    out_xyz[b * 3072]        = cx;
    out_xyz[b * 3072 + 1024] = cy;
    out_xyz[b * 3072 + 2048] = cz;
  }
  for (int t = 1; t < 1024; ++t) {
    {
      float dx = px[0] - cx, dy = py[0] - cy, dz = pz[0] - cz;
      dm[0] = fminf(dm[0], sq3(dx, dy, dz));
    }
    float bv = dm[0];
    int bi = tid * 16;
#pragma unroll
    for (int j = 1; j < 16; ++j) {
      float dx = px[j] - cx, dy = py[j] - cy, dz = pz[j] - cz;
      float d = sq3(dx, dy, dz);
      dm[j] = fminf(dm[j], d);
      if (dm[j] > bv) { bv = dm[j]; bi = tid * 16 + j; }  // strict > keeps lowest idx
    }
    float mx = bv;
    mx = fmaxf(mx, __shfl_xor(mx, 1));
    mx = fmaxf(mx, __shfl_xor(mx, 2));
    mx = fmaxf(mx, __shfl_xor(mx, 4));
    mx = fmaxf(mx, __shfl_xor(mx, 8));
    mx = fmaxf(mx, __shfl_xor(mx, 16));
    mx = fmaxf(mx, __shfl_xor(mx, 32));
    const u64 ball = __ballot(bv == mx);
    const int wl2 = (int)(__ffsll((unsigned long long)ball) - 1);
    const int wbi = __shfl(bi, wl2);
    if ((tid & 63) == 0)
      wkk[t & 1][tid >> 6] = ((u64)__float_as_uint(mx) << 12) | (u32)(4095 - wbi);
    __syncthreads();
    const u64* wk = wkk[t & 1];
    u64 ka = wk[0] > wk[1] ? wk[0] : wk[1];
    u64 kb2 = wk[2] > wk[3] ? wk[2] : wk[3];
    u64 key = ka > kb2 ? ka : kb2;
    const int win = 4095 - (int)(key & 0xfffu);
    const float4 c4 = PS[win];  // single b128 broadcast
    cx = c4.x; cy = c4.y; cz = c4.z;
    if (tid == 0) {
      new_xyzw[(size_t)b * 1024 + t] = make_float4(cx, cy, cz, sq3(cx, cy, cz));
      out_xyz[b * 3072 + t]        = cx;
      out_xyz[b * 3072 + 1024 + t] = cy;
      out_xyz[b * 3072 + 2048 + t] = cz;
    }
  }
}

// ---------- xform helpers ----------
DEV void ln_z(const float* __restrict__ X, u16* __restrict__ ZH, int tid) {
  const int r = tid >> 3, sub = tid & 7;
  const int xm = (r & 7) << 2;
  const float* row = X + r * 128;
  float4 v[4];
  float s = 0.f;
#pragma unroll
  for (int j = 0; j < 4; ++j) {
    v[j] = *(const float4*)&row[(sub * 16 + j * 4) ^ xm];
    s += (v[j].x + v[j].y) + (v[j].z + v[j].w);
  }
  s += __shfl_xor(s, 1); s += __shfl_xor(s, 2); s += __shfl_xor(s, 4);
  const float m = s * 0.0078125f;
  float qv = 0.f;
#pragma unroll
  for (int j = 0; j < 4; ++j) {
    float a = v[j].x - m, b = v[j].y - m, c = v[j].z - m, d = v[j].w - m;
    qv += (a * a + b * b) + (c * c + d * d);
  }
  qv += __shfl_xor(qv, 1); qv += __shfl_xor(qv, 2); qv += __shfl_xor(qv, 4);
  const float rstd = 1.0f / sqrtf(qv * 0.0078125f + 1e-5f);
  const int mask = (r & 7) << 3;
  float z[16];
#pragma unroll
  for (int j = 0; j < 4; ++j) {
    z[j * 4]     = (v[j].x - m) * rstd;
    z[j * 4 + 1] = (v[j].y - m) * rstd;
    z[j * 4 + 2] = (v[j].z - m) * rstd;
    z[j * 4 + 3] = (v[j].w - m) * rstd;
  }
#pragma unroll
  for (int i = 0; i < 8; ++i) {
    const u32 w = f2bfu(z[2 * i]) | (f2bfu(z[2 * i + 1]) << 16);
    *(u32*)&ZH[r * 128 + ((sub * 16 + 2 * i) ^ mask)] = w;
  }
}

template <int K, int AINS, int MODE>
DEV void gemmT(const u16* __restrict__ A, const u16* __restrict__ wbp,
               const float* __restrict__ bias, float* __restrict__ X,
               u16* __restrict__ OUTp, int co, int tid) {
  const int wv = tid >> 6, wl = tid & 63;
  const int c0 = wv * 32;
  const int lm = wl & 15, kb = wl >> 4;
  const int amask = (lm & 7) << 3;
  constexpr int KS = K / 32;
  constexpr int CH = (KS > 4) ? 4 : KS;
  f32x4 acc[4][2];
#pragma unroll
  for (int m = 0; m < 4; ++m)
#pragma unroll
    for (int t = 0; t < 2; ++t) acc[m][t] = (f32x4){0.f, 0.f, 0.f, 0.f};
#pragma unroll
  for (int kc = 0; kc < KS / CH; ++kc) {
    bf16x8 bfr[CH][2];
#pragma unroll
    for (int ks = 0; ks < CH; ++ks) {
      const int k0 = (kc * CH + ks) * 32 + kb * 8;
#pragma unroll
      for (int t = 0; t < 2; ++t)
        bfr[ks][t] = *(const bf16x8*)&wbp[(size_t)(c0 + t * 16 + lm) * K + k0];
    }
#pragma unroll
    for (int ks = 0; ks < CH; ++ks) {
      const int k0 = (kc * CH + ks) * 32 + kb * 8;
      bf16x8 a[4];
#pragma unroll
      for (int m = 0; m < 4; ++m)
        a[m] = *(const bf16x8*)&A[(size_t)(m * 16 + lm) * AINS + (k0 ^ amask)];
#pragma unroll
      for (int m = 0; m < 4; ++m)
#pragma unroll
        for (int t = 0; t < 2; ++t)
          acc[m][t] = MFMA(a[m], bfr[ks][t], acc[m][t]);
    }
  }
#pragma unroll
  for (int m = 0; m < 4; ++m)
#pragma unroll
    for (int t = 0; t < 2; ++t) {
      const int col = c0 + t * 16 + lm;
      const float bv = bias[col];
      if (MODE == 3) {
        const int j0 = (m & 1) * 16 + kb * 4;
        const int base = (m >> 1) * 8192 + (col & 31) * 256 + 128 +
                         ((col >> 5) << 5) + (j0 ^ ((col & 3) << 3));
        *(u32*)&OUTp[base]     = f2bfu(acc[m][t][0] + bv) | (f2bfu(acc[m][t][1] + bv) << 16);
        *(u32*)&OUTp[base + 2] = f2bfu(acc[m][t][2] + bv) | (f2bfu(acc[m][t][3] + bv) << 16);
      } else if (MODE == 1) {
#pragma unroll
        for (int j = 0; j < 4; ++j) {
          const int row = m * 16 + kb * 4 + j;
          X[row * 128 + (col ^ ((row & 7) << 2))] += acc[m][t][j] + bv;
        }
      } else {
#pragma unroll
        for (int j = 0; j < 4; ++j) {
          const int row = m * 16 + kb * 4 + j;
          float val = acc[m][t][j] + bv;
          if (MODE == 2) val = fmaxf(val, 0.f);
          OUTp[row * 256 + ((co + col) ^ ((row & 7) << 3))] = (u16)f2bfu(val);
        }
      }
    }
}

// ---------- fused work kernel: blocks 0..1023 KNN, 1024..5119 xform ----------
__global__ __launch_bounds__(256, 2) void k_work(
    const float* __restrict__ feat, const float* __restrict__ featT, const int useT,
    const float4* __restrict__ xyzw, const float4* __restrict__ newx,
    int* __restrict__ knn, int* __restrict__ flags,
    const float* __restrict__ wf, const float* __restrict__ wp,
    const u16* __restrict__ wb, float* __restrict__ out) {
  __shared__ __align__(16) float sm[20480];
  const int tid = threadIdx.x;

  if (blockIdx.x < 1024) {
    // ---- KNN: 8 queries/block, 32 threads/query, zero LDS ----
    const int k2 = blockIdx.x;
    const int b = k2 & 7, s0 = (k2 >> 3) * 8;
    const int ql = tid >> 5, ss = tid & 31;
    const int s = s0 + ql;
    const float4 Q = newx[(size_t)b * 1024 + s];
    u64 L[32];
#pragma unroll
    for (int i = 0; i < 32; ++i) L[i] = ~0ULL;
    const float4* P = xyzw + (size_t)b * 4096;
#pragma unroll 2
    for (int j = 0; j < 128; ++j) {
      const int n = j * 32 + ss;
      float4 p = P[n];
      float sqd = knn_sqd(Q, p);
      u32 u = __float_as_uint(sqd);
      u ^= (u32)((int)u >> 31) | 0x80000000u;
      const u64 key = ((u64)u << 12) | (u32)n;
      if (key < L[31]) {
#pragma unroll
        for (int i = 31; i >= 1; --i) {
          const u64 lo = L[i] < key ? L[i] : key;
          L[i] = lo > L[i - 1] ? lo : L[i - 1];
        }
        L[0] = L[0] < key ? L[0] : key;
      }
    }
    const size_t ob = ((size_t)b * 1024 + s) * 32;
#pragma unroll 1
    for (int o = 0; o < 32; ++o) {
      u64 mn = L[0];
#pragma unroll
      for (int m2 = 1; m2 < 32; m2 <<= 1) {
        const u64 oth = __shfl_xor(mn, m2, 32);
        mn = oth < mn ? oth : mn;
      }
      const u64 ball = __ballot(L[0] == mn);
      const u32 half = (u32)(ball >> (tid & 32));
      const int wl = __ffs(half) - 1;
      if (ss == 0) knn[ob + o] = (int)(mn & 0xfffu);
      if (ss == wl) {
#pragma unroll
        for (int i = 0; i < 31; ++i) L[i] = L[i + 1];
        L[31] = ~0ULL;
      }
    }
    if (ss == 0)
      __hip_atomic_store(&flags[(s << 3) | b], 1, __ATOMIC_RELEASE, __HIP_MEMORY_SCOPE_AGENT);
    return;
  }

  // ---- xform (M=64 body) ----
  {
    const int bid = blockIdx.x - 1024;
    const int g0 = bid * 2, b = g0 >> 10;
    const int s0 = g0 & 1023;
    if (tid == 0) {
      while (!__hip_atomic_load(&flags[(s0 << 3) | b], __ATOMIC_ACQUIRE, __HIP_MEMORY_SCOPE_AGENT))
        __builtin_amdgcn_s_sleep(8);
      while (!__hip_atomic_load(&flags[((s0 + 1) << 3) | b], __ATOMIC_ACQUIRE, __HIP_MEMORY_SCOPE_AGENT))
        __builtin_amdgcn_s_sleep(8);
    }
    __syncthreads();
    float* X  = sm;                     // [64][128] f32 residual (XOR-swizzled)
    u16* ZH   = (u16*)(sm + 8192);      // [64][128] bf16: h / z / attn-out
    u16* QKp  = (u16*)(sm + 12288);     // [64][256] bf16: Q,K / P,Vt / ff1-out
    const int r = tid >> 3, sub = tid & 7, cs = sub * 16;
    const int xm = (r & 7) << 2;
#pragma unroll
    for (int grp = 0; grp < 2; ++grp) {
      const int n = knn[(g0 + grp) * 32 + r];
      float* dst = &X[(grp * 32 + r) * 128];
      if (useT) {
        const f32x4* srcp = (const f32x4*)(featT + ((size_t)(b * 4096 + n)) * 128 + cs);
#pragma unroll
        for (int j = 0; j < 4; ++j)
          *(f32x4*)&dst[(cs + j * 4) ^ xm] = srcp[j];
      } else {
        const size_t fb0 = (size_t)b * 524288 + n;
#pragma unroll
        for (int j = 0; j < 16; ++j)
          dst[(cs + j) ^ xm] = feat[fb0 + (size_t)(cs + j) * 4096];
      }
      // h = relu(bn(gxyz @ w1.T + b1)) -> ZH bf16 (cols 0..63, swizzled)
      const float4 g4 = xyzw[(size_t)b * 4096 + n];
      const float rs = 1.0f / sqrtf(1.0f + 1e-5f);
      const int mask = (r & 7) << 3;
#pragma unroll
      for (int i = 0; i < 4; ++i) {
        u32 wpk = 0;
#pragma unroll
        for (int e = 0; e < 2; ++e) {
          const int c = sub * 8 + 2 * i + e;
          float hv = g4.x * wf[W_PEW1 + c * 3] + g4.y * wf[W_PEW1 + c * 3 + 1] +
                     g4.z * wf[W_PEW1 + c * 3 + 2] + wf[W_PEB1 + c];
          hv = hv * (wf[W_BNG + c] * rs) + wf[W_BNB + c];
          hv = fmaxf(hv, 0.f);
          wpk |= f2bfu(hv) << (16 * e);
        }
        *(u32*)&ZH[(grp * 32 + r) * 128 + ((sub * 8 + 2 * i) ^ mask)] = wpk;
      }
    }
    __syncthreads();
    gemmT<64, 128, 1>(ZH, wb + WB_P2, wf + W_PEB2, X, QKp, 0, tid);
    __syncthreads();
#pragma unroll 1
    for (int l = 0; l < 2; ++l) {
      ln_z(X, ZH, tid);
      ln_z(X + 4096, ZH + 4096, tid);
      __syncthreads();
      gemmT<128, 128, 0>(ZH, wb + WB_Q + l * 49152, wp + WP_QB + l * 384,
                         X, QKp, 0, tid);
      gemmT<128, 128, 0>(ZH, wb + WB_Q + l * 49152 + 16384,
                         wp + WP_QB + l * 384 + 128, X, QKp, 128, tid);
      __syncthreads();
      // ---- scores + P (one head per wave, both groups) ----
      {
        const int wv = tid >> 6, wl = tid & 63;
        const int hh = wv, lm = wl & 15, kb = wl >> 4;
        bf16x8 qf[2][2], kf[2][2];
#pragma unroll
        for (int grp = 0; grp < 2; ++grp) {
          const u16* Qb = QKp + grp * 8192;
#pragma unroll
          for (int t = 0; t < 2; ++t) {
            const int rr = t * 16 + lm;
            const int msk = (rr & 7) << 3;
            qf[grp][t] = *(const bf16x8*)&Qb[rr * 256 + ((hh * 32 + kb * 8) ^ msk)];
            kf[grp][t] = *(const bf16x8*)&Qb[rr * 256 + ((128 + hh * 32 + kb * 8) ^ msk)];
          }
        }
        __syncthreads();  // all Q/K fragment reads complete before P overwrites Q
        const float scale = 0.1767766952966369f;  // 1/sqrt(32)
        const f32x4 zz = {0.f, 0.f, 0.f, 0.f};
#pragma unroll
        for (int grp = 0; grp < 2; ++grp) {
          f32x4 sc[2][2];
          sc[0][0] = MFMA(qf[grp][0], kf[grp][0], zz);
          sc[0][1] = MFMA(qf[grp][0], kf[grp][1], zz);
          sc[1][0] = MFMA(qf[grp][1], kf[grp][0], zz);
          sc[1][1] = MFMA(qf[grp][1], kf[grp][1], zz);
          u16* Pw = QKp + grp * 8192 + hh * 32;
#pragma unroll
          for (int mtl = 0; mtl < 2; ++mtl) {
#pragma unroll
            for (int j = 0; j < 4; ++j) {
              float a0 = sc[mtl][0][j] * scale, a1 = sc[mtl][1][j] * scale;
              float mx = fmaxf(a0, a1);
              mx = fmaxf(mx, __shfl_xor(mx, 1));
              mx = fmaxf(mx, __shfl_xor(mx, 2));
              mx = fmaxf(mx, __shfl_xor(mx, 4));
              mx = fmaxf(mx, __shfl_xor(mx, 8));
              const float e0 = __expf(a0 - mx), e1 = __expf(a1 - mx);
              float sum = e0 + e1;
              sum += __shfl_xor(sum, 1); sum += __shfl_xor(sum, 2);
              sum += __shfl_xor(sum, 4); sum += __shfl_xor(sum, 8);
              const float inv = 1.0f / sum;
              const int q2 = mtl * 16 + kb * 4 + j;
              const int qm = (q2 & 3) << 3;
              Pw[q2 * 256 + (lm ^ qm)]        = (u16)f2bfu(e0 * inv);
              Pw[q2 * 256 + ((16 + lm) ^ qm)] = (u16)f2bfu(e1 * inv);
            }
          }
        }
      }
      __syncthreads();
      // V gemm -> Vt layout in K-region (K dead after scores), both groups
      gemmT<128, 128, 3>(ZH, wb + WB_Q + l * 49152 + 32768,
                         wp + WP_QB + l * 384 + 256, X, QKp, 0, tid);
      __syncthreads();
      // ---- PV -> attn-out into ZH (z dead after V gemm), both groups ----
      {
        const int wv = tid >> 6, wl = tid & 63;
        const int hh = wv, lm = wl & 15, kb = wl >> 4;
        const f32x4 zz = {0.f, 0.f, 0.f, 0.f};
#pragma unroll
        for (int grp = 0; grp < 2; ++grp) {
          const u16* Qb = QKp + grp * 8192;
          bf16x8 pf[2], vf[2];
#pragma unroll
          for (int t = 0; t < 2; ++t) {
            const int q2 = t * 16 + lm;
            pf[t] = *(const bf16x8*)&Qb[q2 * 256 + hh * 32 +
                                        ((kb * 8) ^ ((q2 & 3) << 3))];
            const int d = hh * 32 + t * 16 + lm;
            vf[t] = *(const bf16x8*)&Qb[(d & 31) * 256 + 128 + hh * 32 +
                                        ((kb * 8) ^ ((d & 3) << 3))];
          }
          f32x4 av[2][2];
          av[0][0] = MFMA(pf[0], vf[0], zz); av[0][1] = MFMA(pf[0], vf[1], zz);
          av[1][0] = MFMA(pf[1], vf[0], zz); av[1][1] = MFMA(pf[1], vf[1], zz);
#pragma unroll
          for (int mtl = 0; mtl < 2; ++mtl)
#pragma unroll
            for (int ntl = 0; ntl < 2; ++ntl)
#pragma unroll
              for (int j = 0; j < 4; ++j) {
                const int row = mtl * 16 + kb * 4 + j;
                const int col = hh * 32 + ntl * 16 + lm;
                ZH[(grp * 32 + row) * 128 + (col ^ ((row & 7) << 3))] =
                    (u16)f2bfu(av[mtl][ntl][j]);
              }
        }
      }
      __syncthreads();
      gemmT<128, 128, 1>(ZH, wb + WB_O + l * 16384, wf + W_OUTB + l * 128,
                         X, QKp, 0, tid);
      __syncthreads();
      ln_z(X, ZH, tid);
      ln_z(X + 4096, ZH + 4096, tid);
      __syncthreads();
      gemmT<128, 128, 2>(ZH, wb + WB_F1 + l * 32768, wp + WP_FB + l * 256,
                         X, QKp, 0, tid);
      gemmT<128, 128, 2>(ZH, wb + WB_F1 + l * 32768 + 16384,
                         wp + WP_FB + l * 256 + 128, X, QKp, 128, tid);
      __syncthreads();
      gemmT<256, 256, 1>(QKp, wb + WB_F2 + l * 32768, wf + W_FF2B + l * 128,
                         X, QKp, 0, tid);
      __syncthreads();
    }
    // pool -> ZH (as f32): pooled[grp*128 + c]
    float* pooled = (float*)ZH;
    if (tid < 128) {
#pragma unroll
      for (int grp = 0; grp < 2; ++grp) {
        const float* Xg = X + grp * 4096;
        float m = Xg[tid];
#pragma unroll
        for (int rr = 1; rr < 32; ++rr)
          m = fmaxf(m, Xg[rr * 128 + (tid ^ ((rr & 7) << 2))]);
        pooled[grp * 128 + tid] = m;
      }
    }
    __syncthreads();
    // fc: both groups
    {
      const float* wr = wf + W_FCW + tid * 128;
      const float bias = wf[W_FCB + tid];
#pragma unroll
      for (int grp = 0; grp < 2; ++grp) {
        float acc = bias;
        const float* pg = pooled + grp * 128;
#pragma unroll 8
        for (int c = 0; c < 128; c += 4) {
          float4 w4 = *(const float4*)&wr[c];
          float4 x4 = *(const float4*)&pg[c];
          acc += dot4(x4, w4);
        }
        const int s = (g0 + grp) & 1023;
        out[24576 + (size_t)b * 262144 + (size_t)tid * 1024 + s] = acc;
      }
    }
  }
}

extern "C" void kernel_launch(void* const* d_in, const int* in_sizes, int n_in,
                              void* d_out, int out_size, void* d_ws, size_t ws_size,
                              hipStream_t stream) {
  (void)in_sizes; (void)n_in; (void)out_size;
  char* ws = (char*)d_ws;
  float* wf    = (float*)ws;
  float4* xyzw = (float4*)(ws + OFF_XYZW);
  float4* newx = (float4*)(ws + OFF_NEWX);
  int* knni    = (int*)(ws + OFF_KNN);
  float* wp    = (float*)(ws + OFF_WP);
  u16* wb      = (u16*)(ws + OFF_WB);
  int* flags   = (int*)(ws + OFF_FLAGS);
  const float* xyz  = (const float*)d_in[0];
  const float* feat = (const float*)d_in[1];
  const int useT = (ws_size >= END_BIG) ? 1 : 0;
  float* featT = useT ? (float*)(ws + OFF_FEATT) : (float*)d_in[1];
  WArgs wa;
  for (int i = 0; i < 20; ++i) wa.p[i] = (const float*)d_in[2 + i];
  float* outp = (float*)d_out;

  hipMemsetAsync(ws + OFF_FLAGS, 0, 32768, stream);
  hipLaunchKernelGGL(k_pre, dim3(useT ? 5438 : 1342), dim3(256), 0, stream,
                     wa, wf, wp, wb, xyz, xyzw, newx, outp, feat, featT, useT);
  hipLaunchKernelGGL(k_work, dim3(5120), dim3(256), 0, stream,
                     feat, featT, useT, xyzw, newx, knni, flags, wf, wp, wb, outp);
}

// Round 22
// 1749.641 us; speedup vs baseline: 1.0245x; 1.0245x over previous
//
#include <hip/hip_runtime.h>

typedef unsigned int u32;
typedef unsigned long long u64;
typedef unsigned short u16;
typedef __attribute__((ext_vector_type(8))) short bf16x8;
typedef __attribute__((ext_vector_type(4))) float f32x4;

#define DEV __device__ __forceinline__

DEV float sq3(float x, float y, float z) {
#pragma clang fp contract(off)
  return (x * x + y * y) + z * z;
}
DEV float knn_sqd(float4 Q, float4 p) {
#pragma clang fp contract(off)
  float dot = (Q.x * p.x + Q.y * p.y) + Q.z * p.z;
  return (Q.w + p.w) - 2.0f * dot;
}
DEV float dot4(float4 a, float4 b) {
  return (a.x * b.x + a.y * b.y) + (a.z * b.z + a.w * b.w);
}
DEV u32 f2bfu(float f) {
  u32 u = __float_as_uint(f);
  return (u + 0x7fffu + ((u >> 16) & 1u)) >> 16;
}
DEV f32x4 MFMA(bf16x8 a, bf16x8 b, f32x4 c) {
  return __builtin_amdgcn_mfma_f32_16x16x32_bf16(a, b, c, 0, 0, 0);
}

// ---------- weight table (f32) ----------
enum : int {
  W_PEW1 = 0, W_PEB1 = 192, W_BNG = 256, W_BNB = 320,
  W_PEW2 = 384, W_PEB2 = 8576,
  W_INW  = 8704,   W_INB  = 107008,
  W_OUTW = 107776, W_OUTB = 140544,
  W_LN1G = 140800, W_LN1B = 141056, W_LN2G = 141312, W_LN2B = 141568,
  W_FF1W = 141824, W_FF1B = 207360,
  W_FF2W = 207872, W_FF2B = 273408,
  W_FCW  = 273664, W_FCB  = 306432,
  W_TOTAL = 306688
};
enum : int { WP_QB = 0, WP_FB = 768, WP_TOTAL = 1280 };
enum : int {
  WB_Q  = 0,       // [2][384][128]
  WB_O  = 98304,   // [2][128][128]
  WB_F1 = 131072,  // [2][256][128]
  WB_F2 = 196608,  // [2][128][256]
  WB_P2 = 262144,  // [128][64]
  WB_TOTAL = 270336
};

// ws byte offsets
static const size_t OFF_XYZW  = 1226752;
static const size_t OFF_NEWX  = 1751040;
static const size_t OFF_KNN   = 1882112;
static const size_t OFF_WP    = 2930688;
static const size_t OFF_WB    = 2936064;
static const size_t OFF_FLAGS = 3476736;  // int[8192]
static const size_t OFF_FEATT = 3509504;  // OPTIONAL [8][4096][128] f32
static const size_t END_BIG   = 20286720;

struct WArgs { const float* p[20]; };

// ---------- k_pre: blocks 0..7 FPS (raw xyz); then transpose; then setup ----------
__global__ __launch_bounds__(256, 1) void k_pre(
    WArgs a, float* __restrict__ wf, float* __restrict__ wp,
    u16* __restrict__ wb, const float* __restrict__ xyz,
    float4* __restrict__ xyzw, float4* __restrict__ new_xyzw,
    float* __restrict__ out_xyz, const float* __restrict__ feat,
    float* __restrict__ featT, const int useT) {
  __shared__ float PXs[4096], PYs[4096], PZs[4096];
  __shared__ u64 wkk[2][4];
  __shared__ float tile[32][33];
  const int tid = threadIdx.x;
  const int blk = blockIdx.x;
  if (blk >= 8) {
    if (useT && blk < 4104) {
      // transpose: features [B][128][4096] -> featT [B][4096][128]
      const int bb = blk - 8;
      const int b = bb >> 9, r2 = bb & 511;
      const int n0 = (r2 >> 2) << 5, c0 = (r2 & 3) << 5;
      const int tx = tid & 31, ty = tid >> 5;
#pragma unroll
      for (int i = 0; i < 4; ++i) {
        const int c = c0 + ty + (i << 3);
        tile[ty + (i << 3)][tx] =
            __builtin_nontemporal_load(&feat[(size_t)b * 524288 + (size_t)c * 4096 + n0 + tx]);
      }
      __syncthreads();
#pragma unroll
      for (int i = 0; i < 4; ++i) {
        const int n = n0 + ty + (i << 3);
        __builtin_nontemporal_store(tile[tx][ty + (i << 3)],
            &featT[(size_t)b * 524288 + (size_t)n * 128 + c0 + tx]);
      }
      return;
    }
    // ---- setup region ----
    const int sblk = blk - (useT ? 4104 : 8);
    if (sblk < 1198) {
      const int idx = sblk * 256 + tid;
      if (idx >= W_TOTAL) return;
      const int sz[20] = {192, 64, 64, 64, 8192, 128, 98304, 768, 32768, 256,
                          256, 256, 256, 256, 65536, 512, 65536, 256, 32768, 256};
      int rem = idx;
#pragma unroll
      for (int s = 0; s < 20; ++s) {
        if (rem < sz[s]) { wf[idx] = a.p[s][rem]; return; }
        rem -= sz[s];
      }
      return;
    }
    if (sblk < 1206) {
      const int idx = (sblk - 1198) * 256 + tid;
      if (idx >= 1920) return;
      if (idx < 768) {  // qkv: fold ln1
        const int l = idx / 384, o = idx % 384;
        const float* W = a.p[6] + l * 49152 + o * 128;
        const float* G = a.p[10] + l * 128;
        const float* Bl = a.p[11] + l * 128;
        float acc = a.p[7][l * 384 + o];
        u16* ph = wb + WB_Q + (l * 384 + o) * 128;
        for (int c = 0; c < 128; ++c) {
          const float w = W[c];
          acc += Bl[c] * w;
          ph[c] = (u16)f2bfu(w * G[c]);
        }
        wp[WP_QB + l * 384 + o] = acc;
      } else if (idx < 1280) {  // ff1: fold ln2
        const int j2 = idx - 768, l = j2 / 256, o = j2 % 256;
        const float* W = a.p[14] + l * 32768 + o * 128;
        const float* G = a.p[12] + l * 128;
        const float* Bl = a.p[13] + l * 128;
        float acc = a.p[15][l * 256 + o];
        u16* ph = wb + WB_F1 + (l * 256 + o) * 128;
        for (int c = 0; c < 128; ++c) {
          const float w = W[c];
          acc += Bl[c] * w;
          ph[c] = (u16)f2bfu(w * G[c]);
        }
        wp[WP_FB + l * 256 + o] = acc;
      } else if (idx < 1536) {  // out-proj
        const int j2 = idx - 1280, l = j2 / 128, o = j2 % 128;
        const float* W = a.p[8] + l * 16384 + o * 128;
        u16* ph = wb + WB_O + (l * 128 + o) * 128;
        for (int c = 0; c < 128; ++c) ph[c] = (u16)f2bfu(W[c]);
      } else if (idx < 1792) {  // ff2
        const int j2 = idx - 1536, l = j2 / 128, o = j2 % 128;
        const float* W = a.p[16] + l * 32768 + o * 256;
        u16* ph = wb + WB_F2 + (l * 128 + o) * 256;
        for (int c = 0; c < 256; ++c) ph[c] = (u16)f2bfu(W[c]);
      } else {  // pe_w2
        const int o = idx - 1792;
        const float* W = a.p[4] + o * 64;
        u16* ph = wb + WB_P2 + o * 64;
        for (int c = 0; c < 64; ++c) ph[c] = (u16)f2bfu(W[c]);
      }
      return;
    }
    {
      const int i = (sblk - 1206) * 256 + tid;
      const int b = i >> 12, n = i & 4095;
      const size_t s = (size_t)b * 12288 + n;
      float x = xyz[s], y = xyz[s + 4096], z = xyz[s + 8192];
      xyzw[i] = make_float4(x, y, z, sq3(x, y, z));
      return;
    }
  }
  // ---- FPS — exact replica of reference scan (reads raw xyz) ----
  const int b = blk;
  const size_t sb = (size_t)b * 12288;
  float px[16], py[16], pz[16], dm[16];
#pragma unroll
  for (int j = 0; j < 16; ++j) {
    const int n = tid * 16 + j;
    float x = xyz[sb + n], y = xyz[sb + 4096 + n], z = xyz[sb + 8192 + n];
    PXs[n] = x; PYs[n] = y; PZs[n] = z;
    px[j] = x; py[j] = y; pz[j] = z; dm[j] = 1e10f;
  }
  __syncthreads();
  float cx = PXs[0], cy = PYs[0], cz = PZs[0];
  if (tid == 0) {
    new_xyzw[(size_t)b * 1024] = make_float4(cx, cy, cz, sq3(cx, cy, cz));
    out_xyz[b * 3072]        = cx;
    out_xyz[b * 3072 + 1024] = cy;
    out_xyz[b * 3072 + 2048] = cz;
  }
  for (int t = 1; t < 1024; ++t) {
    {
      float dx = px[0] - cx, dy = py[0] - cy, dz = pz[0] - cz;
      dm[0] = fminf(dm[0], sq3(dx, dy, dz));
    }
    float bv = dm[0];
    int bi = tid * 16;
#pragma unroll
    for (int j = 1; j < 16; ++j) {
      float dx = px[j] - cx, dy = py[j] - cy, dz = pz[j] - cz;
      float d = sq3(dx, dy, dz);
      dm[j] = fminf(dm[j], d);
      if (dm[j] > bv) { bv = dm[j]; bi = tid * 16 + j; }
    }
    float mx = bv;
    mx = fmaxf(mx, __shfl_xor(mx, 1));
    mx = fmaxf(mx, __shfl_xor(mx, 2));
    mx = fmaxf(mx, __shfl_xor(mx, 4));
    mx = fmaxf(mx, __shfl_xor(mx, 8));
    mx = fmaxf(mx, __shfl_xor(mx, 16));
    mx = fmaxf(mx, __shfl_xor(mx, 32));
    const u64 ball = __ballot(bv == mx);
    const int wl2 = (int)(__ffsll((unsigned long long)ball) - 1);
    const int wbi = __shfl(bi, wl2);
    if ((tid & 63) == 0)
      wkk[t & 1][tid >> 6] = ((u64)__float_as_uint(mx) << 12) | (u32)(4095 - wbi);
    __syncthreads();
    const u64* wk = wkk[t & 1];
    u64 ka = wk[0] > wk[1] ? wk[0] : wk[1];
    u64 kb2 = wk[2] > wk[3] ? wk[2] : wk[3];
    u64 key = ka > kb2 ? ka : kb2;
    const int win = 4095 - (int)(key & 0xfffu);
    cx = PXs[win]; cy = PYs[win]; cz = PZs[win];
    if (tid == 0) {
      new_xyzw[(size_t)b * 1024 + t] = make_float4(cx, cy, cz, sq3(cx, cy, cz));
      out_xyz[b * 3072 + t]        = cx;
      out_xyz[b * 3072 + 1024 + t] = cy;
      out_xyz[b * 3072 + 2048 + t] = cz;
    }
  }
}

// ---------- xform helpers ----------
DEV void ln_z(const float* __restrict__ X, u16* __restrict__ ZH, int tid) {
  const int r = tid >> 3, sub = tid & 7;
  const int xm = (r & 7) << 2;
  const float* row = X + r * 128;
  float4 v[4];
  float s = 0.f;
#pragma unroll
  for (int j = 0; j < 4; ++j) {
    v[j] = *(const float4*)&row[(sub * 16 + j * 4) ^ xm];
    s += (v[j].x + v[j].y) + (v[j].z + v[j].w);
  }
  s += __shfl_xor(s, 1); s += __shfl_xor(s, 2); s += __shfl_xor(s, 4);
  const float m = s * 0.0078125f;
  float qv = 0.f;
#pragma unroll
  for (int j = 0; j < 4; ++j) {
    float a = v[j].x - m, b = v[j].y - m, c = v[j].z - m, d = v[j].w - m;
    qv += (a * a + b * b) + (c * c + d * d);
  }
  qv += __shfl_xor(qv, 1); qv += __shfl_xor(qv, 2); qv += __shfl_xor(qv, 4);
  const float rstd = 1.0f / sqrtf(qv * 0.0078125f + 1e-5f);
  const int mask = (r & 7) << 3;
  float z[16];
#pragma unroll
  for (int j = 0; j < 4; ++j) {
    z[j * 4]     = (v[j].x - m) * rstd;
    z[j * 4 + 1] = (v[j].y - m) * rstd;
    z[j * 4 + 2] = (v[j].z - m) * rstd;
    z[j * 4 + 3] = (v[j].w - m) * rstd;
  }
#pragma unroll
  for (int i = 0; i < 8; ++i) {
    const u32 w = f2bfu(z[2 * i]) | (f2bfu(z[2 * i + 1]) << 16);
    *(u32*)&ZH[r * 128 + ((sub * 16 + 2 * i) ^ mask)] = w;
  }
}

template <int K, int AINS, int MODE>
DEV void gemmT(const u16* __restrict__ A, const u16* __restrict__ wbp,
               const float* __restrict__ bias, float* __restrict__ X,
               u16* __restrict__ OUTp, int co, int tid) {
  const int wv = tid >> 6, wl = tid & 63;
  const int c0 = wv * 32;
  const int lm = wl & 15, kb = wl >> 4;
  const int amask = (lm & 7) << 3;
  constexpr int KS = K / 32;
  constexpr int CH = (KS > 4) ? 4 : KS;
  f32x4 acc[4][2];
#pragma unroll
  for (int m = 0; m < 4; ++m)
#pragma unroll
    for (int t = 0; t < 2; ++t) acc[m][t] = (f32x4){0.f, 0.f, 0.f, 0.f};
#pragma unroll
  for (int kc = 0; kc < KS / CH; ++kc) {
    bf16x8 bfr[CH][2];
#pragma unroll
    for (int ks = 0; ks < CH; ++ks) {
      const int k0 = (kc * CH + ks) * 32 + kb * 8;
#pragma unroll
      for (int t = 0; t < 2; ++t)
        bfr[ks][t] = *(const bf16x8*)&wbp[(size_t)(c0 + t * 16 + lm) * K + k0];
    }
#pragma unroll
    for (int ks = 0; ks < CH; ++ks) {
      const int k0 = (kc * CH + ks) * 32 + kb * 8;
      bf16x8 a[4];
#pragma unroll
      for (int m = 0; m < 4; ++m)
        a[m] = *(const bf16x8*)&A[(size_t)(m * 16 + lm) * AINS + (k0 ^ amask)];
#pragma unroll
      for (int m = 0; m < 4; ++m)
#pragma unroll
        for (int t = 0; t < 2; ++t)
          acc[m][t] = MFMA(a[m], bfr[ks][t], acc[m][t]);
    }
  }
#pragma unroll
  for (int m = 0; m < 4; ++m)
#pragma unroll
    for (int t = 0; t < 2; ++t) {
      const int col = c0 + t * 16 + lm;
      const float bv = bias[col];
      if (MODE == 3) {
        const int j0 = (m & 1) * 16 + kb * 4;
        const int base = (m >> 1) * 8192 + (col & 31) * 256 + 128 +
                         ((col >> 5) << 5) + (j0 ^ ((col & 3) << 3));
        *(u32*)&OUTp[base]     = f2bfu(acc[m][t][0] + bv) | (f2bfu(acc[m][t][1] + bv) << 16);
        *(u32*)&OUTp[base + 2] = f2bfu(acc[m][t][2] + bv) | (f2bfu(acc[m][t][3] + bv) << 16);
      } else if (MODE == 1) {
#pragma unroll
        for (int j = 0; j < 4; ++j) {
          const int row = m * 16 + kb * 4 + j;
          X[row * 128 + (col ^ ((row & 7) << 2))] += acc[m][t][j] + bv;
        }
      } else {
#pragma unroll
        for (int j = 0; j < 4; ++j) {
          const int row = m * 16 + kb * 4 + j;
          float val = acc[m][t][j] + bv;
          if (MODE == 2) val = fmaxf(val, 0.f);
          OUTp[row * 256 + ((co + col) ^ ((row & 7) << 3))] = (u16)f2bfu(val);
        }
      }
    }
}

// ---------- fused work kernel: blocks 0..1023 KNN, 1024..5119 xform ----------
__global__ __launch_bounds__(256, 2) void k_work(
    const float* __restrict__ feat, const float* __restrict__ featT, const int useT,
    const float4* __restrict__ xyzw, const float4* __restrict__ newx,
    int* __restrict__ knn, int* __restrict__ flags,
    const float* __restrict__ wf, const float* __restrict__ wp,
    const u16* __restrict__ wb, float* __restrict__ out) {
  __shared__ __align__(16) float sm[20480];
  const int tid = threadIdx.x;

  if (blockIdx.x < 1024) {
    // ---- KNN: 8 queries/block, 32 threads/query, zero LDS ----
    const int k2 = blockIdx.x;
    const int b = k2 & 7, s0 = (k2 >> 3) * 8;
    const int ql = tid >> 5, ss = tid & 31;
    const int s = s0 + ql;
    const float4 Q = newx[(size_t)b * 1024 + s];
    u64 L[32];
#pragma unroll
    for (int i = 0; i < 32; ++i) L[i] = ~0ULL;
    const float4* P = xyzw + (size_t)b * 4096;
#pragma unroll 2
    for (int j = 0; j < 128; ++j) {
      const int n = j * 32 + ss;
      float4 p = P[n];
      float sqd = knn_sqd(Q, p);
      u32 u = __float_as_uint(sqd);
      u ^= (u32)((int)u >> 31) | 0x80000000u;
      const u64 key = ((u64)u << 12) | (u32)n;
      if (key < L[31]) {
#pragma unroll
        for (int i = 31; i >= 1; --i) {
          const u64 lo = L[i] < key ? L[i] : key;
          L[i] = lo > L[i - 1] ? lo : L[i - 1];
        }
        L[0] = L[0] < key ? L[0] : key;
      }
    }
    const size_t ob = ((size_t)b * 1024 + s) * 32;
#pragma unroll 1
    for (int o = 0; o < 32; ++o) {
      u64 mn = L[0];
#pragma unroll
      for (int m2 = 1; m2 < 32; m2 <<= 1) {
        const u64 oth = __shfl_xor(mn, m2, 32);
        mn = oth < mn ? oth : mn;
      }
      const u64 ball = __ballot(L[0] == mn);
      const u32 half = (u32)(ball >> (tid & 32));
      const int wl = __ffs(half) - 1;
      if (ss == 0) knn[ob + o] = (int)(mn & 0xfffu);
      if (ss == wl) {
#pragma unroll
        for (int i = 0; i < 31; ++i) L[i] = L[i + 1];
        L[31] = ~0ULL;
      }
    }
    if (ss == 0)
      __hip_atomic_store(&flags[(s << 3) | b], 1, __ATOMIC_RELEASE, __HIP_MEMORY_SCOPE_AGENT);
    return;
  }

  // ---- xform (M=64 body) ----
  {
    const int bid = blockIdx.x - 1024;
    const int g0 = bid * 2, b = g0 >> 10;
    const int s0 = g0 & 1023;
    if (tid == 0) {
      while (!__hip_atomic_load(&flags[(s0 << 3) | b], __ATOMIC_ACQUIRE, __HIP_MEMORY_SCOPE_AGENT))
        __builtin_amdgcn_s_sleep(8);
      while (!__hip_atomic_load(&flags[((s0 + 1) << 3) | b], __ATOMIC_ACQUIRE, __HIP_MEMORY_SCOPE_AGENT))
        __builtin_amdgcn_s_sleep(8);
    }
    __syncthreads();
    float* X  = sm;                     // [64][128] f32 residual (XOR-swizzled)
    u16* ZH   = (u16*)(sm + 8192);      // [64][128] bf16: h / z / attn-out
    u16* QKp  = (u16*)(sm + 12288);     // [64][256] bf16: Q,K / P,Vt / ff1-out
    const int r = tid >> 3, sub = tid & 7, cs = sub * 16;
    const int xm = (r & 7) << 2;
#pragma unroll
    for (int grp = 0; grp < 2; ++grp) {
      const int n = knn[(g0 + grp) * 32 + r];
      float* dst = &X[(grp * 32 + r) * 128];
      if (useT) {
        const f32x4* srcp = (const f32x4*)(featT + ((size_t)(b * 4096 + n)) * 128 + cs);
#pragma unroll
        for (int j = 0; j < 4; ++j)
          *(f32x4*)&dst[(cs + j * 4) ^ xm] = srcp[j];
      } else {
        const size_t fb0 = (size_t)b * 524288 + n;
#pragma unroll
        for (int j = 0; j < 16; ++j)
          dst[(cs + j) ^ xm] = feat[fb0 + (size_t)(cs + j) * 4096];
      }
      // h = relu(bn(gxyz @ w1.T + b1)) -> ZH bf16 (cols 0..63, swizzled)
      const float4 g4 = xyzw[(size_t)b * 4096 + n];
      const float rs = 1.0f / sqrtf(1.0f + 1e-5f);
      const int mask = (r & 7) << 3;
#pragma unroll
      for (int i = 0; i < 4; ++i) {
        u32 wpk = 0;
#pragma unroll
        for (int e = 0; e < 2; ++e) {
          const int c = sub * 8 + 2 * i + e;
          float hv = g4.x * wf[W_PEW1 + c * 3] + g4.y * wf[W_PEW1 + c * 3 + 1] +
                     g4.z * wf[W_PEW1 + c * 3 + 2] + wf[W_PEB1 + c];
          hv = hv * (wf[W_BNG + c] * rs) + wf[W_BNB + c];
          hv = fmaxf(hv, 0.f);
          wpk |= f2bfu(hv) << (16 * e);
        }
        *(u32*)&ZH[(grp * 32 + r) * 128 + ((sub * 8 + 2 * i) ^ mask)] = wpk;
      }
    }
    __syncthreads();
    gemmT<64, 128, 1>(ZH, wb + WB_P2, wf + W_PEB2, X, QKp, 0, tid);
    __syncthreads();
#pragma unroll 1
    for (int l = 0; l < 2; ++l) {
      ln_z(X, ZH, tid);
      ln_z(X + 4096, ZH + 4096, tid);
      __syncthreads();
      gemmT<128, 128, 0>(ZH, wb + WB_Q + l * 49152, wp + WP_QB + l * 384,
                         X, QKp, 0, tid);
      gemmT<128, 128, 0>(ZH, wb + WB_Q + l * 49152 + 16384,
                         wp + WP_QB + l * 384 + 128, X, QKp, 128, tid);
      __syncthreads();
      // ---- scores + P (one head per wave, both groups) ----
      {
        const int wv = tid >> 6, wl = tid & 63;
        const int hh = wv, lm = wl & 15, kb = wl >> 4;
        bf16x8 qf[2][2], kf[2][2];
#pragma unroll
        for (int grp = 0; grp < 2; ++grp) {
          const u16* Qb = QKp + grp * 8192;
#pragma unroll
          for (int t = 0; t < 2; ++t) {
            const int rr = t * 16 + lm;
            const int msk = (rr & 7) << 3;
            qf[grp][t] = *(const bf16x8*)&Qb[rr * 256 + ((hh * 32 + kb * 8) ^ msk)];
            kf[grp][t] = *(const bf16x8*)&Qb[rr * 256 + ((128 + hh * 32 + kb * 8) ^ msk)];
          }
        }
        __syncthreads();  // all Q/K fragment reads complete before P overwrites Q
        const float scale = 0.1767766952966369f;  // 1/sqrt(32)
        const f32x4 zz = {0.f, 0.f, 0.f, 0.f};
#pragma unroll
        for (int grp = 0; grp < 2; ++grp) {
          f32x4 sc[2][2];
          sc[0][0] = MFMA(qf[grp][0], kf[grp][0], zz);
          sc[0][1] = MFMA(qf[grp][0], kf[grp][1], zz);
          sc[1][0] = MFMA(qf[grp][1], kf[grp][0], zz);
          sc[1][1] = MFMA(qf[grp][1], kf[grp][1], zz);
          u16* Pw = QKp + grp * 8192 + hh * 32;
#pragma unroll
          for (int mtl = 0; mtl < 2; ++mtl) {
#pragma unroll
            for (int j = 0; j < 4; ++j) {
              float a0 = sc[mtl][0][j] * scale, a1 = sc[mtl][1][j] * scale;
              float mx = fmaxf(a0, a1);
              mx = fmaxf(mx, __shfl_xor(mx, 1));
              mx = fmaxf(mx, __shfl_xor(mx, 2));
              mx = fmaxf(mx, __shfl_xor(mx, 4));
              mx = fmaxf(mx, __shfl_xor(mx, 8));
              const float e0 = __expf(a0 - mx), e1 = __expf(a1 - mx);
              float sum = e0 + e1;
              sum += __shfl_xor(sum, 1); sum += __shfl_xor(sum, 2);
              sum += __shfl_xor(sum, 4); sum += __shfl_xor(sum, 8);
              const float inv = 1.0f / sum;
              const int q2 = mtl * 16 + kb * 4 + j;
              const int qm = (q2 & 3) << 3;
              Pw[q2 * 256 + (lm ^ qm)]        = (u16)f2bfu(e0 * inv);
              Pw[q2 * 256 + ((16 + lm) ^ qm)] = (u16)f2bfu(e1 * inv);
            }
          }
        }
      }
      __syncthreads();
      // V gemm -> Vt layout in K-region (K dead after scores), both groups
      gemmT<128, 128, 3>(ZH, wb + WB_Q + l * 49152 + 32768,
                         wp + WP_QB + l * 384 + 256, X, QKp, 0, tid);
      __syncthreads();
      // ---- PV -> attn-out into ZH (z dead after V gemm), both groups ----
      {
        const int wv = tid >> 6, wl = tid & 63;
        const int hh = wv, lm = wl & 15, kb = wl >> 4;
        const f32x4 zz = {0.f, 0.f, 0.f, 0.f};
#pragma unroll
        for (int grp = 0; grp < 2; ++grp) {
          const u16* Qb = QKp + grp * 8192;
          bf16x8 pf[2], vf[2];
#pragma unroll
          for (int t = 0; t < 2; ++t) {
            const int q2 = t * 16 + lm;
            pf[t] = *(const bf16x8*)&Qb[q2 * 256 + hh * 32 +
                                        ((kb * 8) ^ ((q2 & 3) << 3))];
            const int d = hh * 32 + t * 16 + lm;
            vf[t] = *(const bf16x8*)&Qb[(d & 31) * 256 + 128 + hh * 32 +
                                        ((kb * 8) ^ ((d & 3) << 3))];
          }
          f32x4 av[2][2];
          av[0][0] = MFMA(pf[0], vf[0], zz); av[0][1] = MFMA(pf[0], vf[1], zz);
          av[1][0] = MFMA(pf[1], vf[0], zz); av[1][1] = MFMA(pf[1], vf[1], zz);
#pragma unroll
          for (int mtl = 0; mtl < 2; ++mtl)
#pragma unroll
            for (int ntl = 0; ntl < 2; ++ntl)
#pragma unroll
              for (int j = 0; j < 4; ++j) {
                const int row = mtl * 16 + kb * 4 + j;
                const int col = hh * 32 + ntl * 16 + lm;
                ZH[(grp * 32 + row) * 128 + (col ^ ((row & 7) << 3))] =
                    (u16)f2bfu(av[mtl][ntl][j]);
              }
        }
      }
      __syncthreads();
      gemmT<128, 128, 1>(ZH, wb + WB_O + l * 16384, wf + W_OUTB + l * 128,
                         X, QKp, 0, tid);
      __syncthreads();
      ln_z(X, ZH, tid);
      ln_z(X + 4096, ZH + 4096, tid);
      __syncthreads();
      gemmT<128, 128, 2>(ZH, wb + WB_F1 + l * 32768, wp + WP_FB + l * 256,
                         X, QKp, 0, tid);
      gemmT<128, 128, 2>(ZH, wb + WB_F1 + l * 32768 + 16384,
                         wp + WP_FB + l * 256 + 128, X, QKp, 128, tid);
      __syncthreads();
      gemmT<256, 256, 1>(QKp, wb + WB_F2 + l * 32768, wf + W_FF2B + l * 128,
                         X, QKp, 0, tid);
      __syncthreads();
    }
    // pool -> ZH (as f32): pooled[grp*128 + c]
    float* pooled = (float*)ZH;
    if (tid < 128) {
#pragma unroll
      for (int grp = 0; grp < 2; ++grp) {
        const float* Xg = X + grp * 4096;
        float m = Xg[tid];
#pragma unroll
        for (int rr = 1; rr < 32; ++rr)
          m = fmaxf(m, Xg[rr * 128 + (tid ^ ((rr & 7) << 2))]);
        pooled[grp * 128 + tid] = m;
      }
    }
    __syncthreads();
    // fc: both groups
    {
      const float* wr = wf + W_FCW + tid * 128;
      const float bias = wf[W_FCB + tid];
#pragma unroll
      for (int grp = 0; grp < 2; ++grp) {
        float acc = bias;
        const float* pg = pooled + grp * 128;
#pragma unroll 8
        for (int c = 0; c < 128; c += 4) {
          float4 w4 = *(const float4*)&wr[c];
          float4 x4 = *(const float4*)&pg[c];
          acc += dot4(x4, w4);
        }
        const int s = (g0 + grp) & 1023;
        out[24576 + (size_t)b * 262144 + (size_t)tid * 1024 + s] = acc;
      }
    }
  }
}

extern "C" void kernel_launch(void* const* d_in, const int* in_sizes, int n_in,
                              void* d_out, int out_size, void* d_ws, size_t ws_size,
                              hipStream_t stream) {
  (void)in_sizes; (void)n_in; (void)out_size;
  char* ws = (char*)d_ws;
  float* wf    = (float*)ws;
  float4* xyzw = (float4*)(ws + OFF_XYZW);
  float4* newx = (float4*)(ws + OFF_NEWX);
  int* knni    = (int*)(ws + OFF_KNN);
  float* wp    = (float*)(ws + OFF_WP);
  u16* wb      = (u16*)(ws + OFF_WB);
  int* flags   = (int*)(ws + OFF_FLAGS);
  const float* xyz  = (const float*)d_in[0];
  const float* feat = (const float*)d_in[1];
  const int useT = (ws_size >= END_BIG) ? 1 : 0;
  float* featT = useT ? (float*)(ws + OFF_FEATT) : (float*)d_in[1];
  WArgs wa;
  for (int i = 0; i < 20; ++i) wa.p[i] = (const float*)d_in[2 + i];
  float* outp = (float*)d_out;

  hipMemsetAsync(ws + OFF_FLAGS, 0, 32768, stream);
  hipLaunchKernelGGL(k_pre, dim3(useT ? 5438 : 1342), dim3(256), 0, stream,
                     wa, wf, wp, wb, xyz, xyzw, newx, outp, feat, featT, useT);
  hipLaunchKernelGGL(k_work, dim3(5120), dim3(256), 0, stream,
                     feat, featT, useT, xyzw, newx, knni, flags, wf, wp, wb, outp);
}